// Round 3
// baseline (2454.709 us; speedup 1.0000x reference)
//
#include <hip/hip_runtime.h>
#include <hip/hip_bf16.h>

// BitNet FFN: LN -> act_quant/ternary-W matmul -> GELU(erf) -> act_quant/ternary-W matmul
// Shapes: x[4,4096,2048] f32, w1[8192,2048], w2[2048,8192], out [16384,2048] f32.
// R3: two-pass GEMM1 (amax pass + quant pass) keeps h at register precision --
// no f32 h storage. Peak workspace 357 MiB (< proven-working 385 MiB).
// GEMMs remain integer-exact bf16 MFMA (ints <=127 exact in bf16, f32 accum exact).

typedef __attribute__((ext_vector_type(8))) short short8;
typedef __attribute__((ext_vector_type(4))) float floatx4;

#define D_DIM 2048
#define H_DIM 8192
#define M_DIM 16384

// ---------- small helpers ----------
__device__ __forceinline__ float bf2f(unsigned short u) {
  unsigned int x = ((unsigned int)u) << 16;
  return __builtin_bit_cast(float, x);
}
__device__ __forceinline__ unsigned short f2bf(float f) {
  unsigned int u = __builtin_bit_cast(unsigned int, f);
  u += 0x7FFFu + ((u >> 16) & 1u);   // RNE; inputs here are never NaN
  return (unsigned short)(u >> 16);
}

__device__ __forceinline__ float block_sum(float v, float* buf) {
#pragma unroll
  for (int o = 32; o > 0; o >>= 1) v += __shfl_down(v, o, 64);
  const int lane = threadIdx.x & 63, w = threadIdx.x >> 6;
  if (lane == 0) buf[w] = v;
  __syncthreads();
  float r = buf[0] + buf[1] + buf[2] + buf[3];
  __syncthreads();
  return r;
}
__device__ __forceinline__ float block_max(float v, float* buf) {
#pragma unroll
  for (int o = 32; o > 0; o >>= 1) v = fmaxf(v, __shfl_down(v, o, 64));
  const int lane = threadIdx.x & 63, w = threadIdx.x >> 6;
  if (lane == 0) buf[w] = v;
  __syncthreads();
  float r = fmaxf(fmaxf(buf[0], buf[1]), fmaxf(buf[2], buf[3]));
  __syncthreads();
  return r;
}

__device__ __forceinline__ void lds16(const unsigned short* g, unsigned short* l) {
  __builtin_amdgcn_global_load_lds(
      (const __attribute__((address_space(1))) unsigned int*)g,
      (__attribute__((address_space(3))) unsigned int*)l, 16, 0, 0);
}

// ---------- weight abs-mean (deterministic two-stage) ----------
__global__ __launch_bounds__(256) void absmean_partial(const float* __restrict__ w,
                                                       int n, double* __restrict__ part) {
  __shared__ float buf[4];
  float s = 0.0f;
  const long stride = (long)gridDim.x * 256 * 4;
  for (long i = ((long)blockIdx.x * 256 + threadIdx.x) * 4; i < n; i += stride) {
    float4 v = *(const float4*)(w + i);
    s += fabsf(v.x) + fabsf(v.y) + fabsf(v.z) + fabsf(v.w);
  }
  float r = block_sum(s, buf);
  if (threadIdx.x == 0) part[blockIdx.x] = (double)r;
}

__global__ __launch_bounds__(256) void absmean_final(const double* __restrict__ part,
                                                     int nb, double n, double* __restrict__ out) {
  __shared__ double buf[4];
  double s = 0.0;
  for (int i = threadIdx.x; i < nb; i += 256) s += part[i];
#pragma unroll
  for (int o = 32; o > 0; o >>= 1) s += __shfl_down(s, o, 64);
  const int lane = threadIdx.x & 63, w = threadIdx.x >> 6;
  if (lane == 0) buf[w] = s;
  __syncthreads();
  if (threadIdx.x == 0) out[0] = (buf[0] + buf[1] + buf[2] + buf[3]) / n;
}

// ---------- ternary weight quant: t = clip(rint(w*s),-1,1), stored as bf16 ----------
__global__ __launch_bounds__(256) void wquant_kernel(const float* __restrict__ w,
                                                     const double* __restrict__ mean,
                                                     unsigned short* __restrict__ wq, int n) {
  long i = ((long)blockIdx.x * 256 + threadIdx.x) * 4;
  if (i >= n) return;
  const float s = 1.0f / (float)fmax(mean[0], 1e-5);
  float4 v = *(const float4*)(w + i);
  ushort4 q;
  q.x = f2bf(fminf(fmaxf(rintf(v.x * s), -1.f), 1.f));
  q.y = f2bf(fminf(fmaxf(rintf(v.y * s), -1.f), 1.f));
  q.z = f2bf(fminf(fmaxf(rintf(v.z * s), -1.f), 1.f));
  q.w = f2bf(fminf(fmaxf(rintf(v.w * s), -1.f), 1.f));
  *(ushort4*)(wq + i) = q;
}

// ---------- fused LayerNorm + per-token int8 absmax quant ----------
__global__ __launch_bounds__(256) void ln_quant_kernel(const float* __restrict__ x,
                                                       const float* __restrict__ gamma,
                                                       const float* __restrict__ beta,
                                                       unsigned short* __restrict__ aq,
                                                       float* __restrict__ ds) {
  __shared__ float buf[4];
  const int t = threadIdx.x;
  const long row = blockIdx.x;
  const float* xr = x + row * (long)D_DIM;
  float v[8];
  *(float4*)(v)     = *(const float4*)(xr + t * 8);
  *(float4*)(v + 4) = *(const float4*)(xr + t * 8 + 4);
  float s = 0.f;
#pragma unroll
  for (int i = 0; i < 8; ++i) s += v[i];
  s = block_sum(s, buf);
  const float mu = s * (1.0f / 2048.0f);
  float sq = 0.f;
#pragma unroll
  for (int i = 0; i < 8; ++i) { float d = v[i] - mu; sq += d * d; }
  sq = block_sum(sq, buf);
  const float inv = 1.0f / sqrtf(sq * (1.0f / 2048.0f) + 1e-5f);
  float gam[8], bet[8];
  *(float4*)(gam)     = *(const float4*)(gamma + t * 8);
  *(float4*)(gam + 4) = *(const float4*)(gamma + t * 8 + 4);
  *(float4*)(bet)     = *(const float4*)(beta + t * 8);
  *(float4*)(bet + 4) = *(const float4*)(beta + t * 8 + 4);
  float xn[8]; float am = 0.f;
#pragma unroll
  for (int i = 0; i < 8; ++i) {
    xn[i] = (v[i] - mu) * inv * gam[i] + bet[i];
    am = fmaxf(am, fabsf(xn[i]));
  }
  am = block_max(am, buf);
  am = fmaxf(am, 1e-5f);
  const float qs = 127.0f / am;
  __align__(16) unsigned short q[8];
#pragma unroll
  for (int i = 0; i < 8; ++i)
    q[i] = f2bf(fminf(fmaxf(rintf(xn[i] * qs), -128.f), 127.f));
  *(ushort4*)(aq + row * D_DIM + t * 8)     = *(ushort4*)(q);
  *(ushort4*)(aq + row * D_DIM + t * 8 + 4) = *(ushort4*)(q + 4);
  if (t == 0) ds[row] = am / 127.0f;
}

// ---------- reduce 64 per-block partial maxes -> rmax (clipped) and ds2 ----------
__global__ __launch_bounds__(256) void rowmax_kernel(const float* __restrict__ amax,
                                                     float* __restrict__ rmax,
                                                     float* __restrict__ ds2) {
  const int w = threadIdx.x >> 6, lane = threadIdx.x & 63;
  const long row = (long)blockIdx.x * 4 + w;
  float v = amax[row * 64 + lane];
#pragma unroll
  for (int o = 32; o > 0; o >>= 1) v = fmaxf(v, __shfl_down(v, o, 64));
  if (lane == 0) {
    const float mc = fmaxf(v, 1e-5f);
    rmax[row] = mc;
    ds2[row] = mc / 127.0f;
  }
}

// ---------- m97-style 128x128 GEMM, A[M,K] x B[N,K]^T, templated epilogue ----------
// EPI==0: dequant+bias+GELU, per-row |g| block-max -> amaxo[row*64 + bx]  (GEMM1 pass A)
// EPI==1: dequant+bias+GELU, quantize with 127/rmax[row] -> bf16 int outh (GEMM1 pass B)
// EPI==2: dequant+bias -> f32 outf                                        (GEMM2)
template <int EPI>
__global__ __launch_bounds__(256) void gemm_kernel(const unsigned short* __restrict__ A,
                                                   const unsigned short* __restrict__ Bm,
                                                   const float* __restrict__ dsA,
                                                   const double* __restrict__ meanw,
                                                   const float* __restrict__ bias,
                                                   float* __restrict__ outf,
                                                   unsigned short* __restrict__ outh,
                                                   float* __restrict__ amaxo,
                                                   const float* __restrict__ rmaxin,
                                                   int N, int K) {
  __shared__ __align__(16) unsigned short smA[128 * 32];
  __shared__ __align__(16) unsigned short smB[128 * 32];
  __shared__ unsigned int smx[128];
  const int tid = threadIdx.x;
  const int lane = tid & 63;
  const int wid = tid >> 6;
  const int wr = wid >> 1, wc = wid & 1;   // 2x2 waves, 64x64 each
  const int r0blk = blockIdx.y * 128;
  const long Brow0 = (long)blockIdx.x * 128;

  if (EPI == 0 && tid < 128) smx[tid] = 0u;   // ordered before use by loop barriers

  const int erow = tid >> 2;               // staging row (0..63)
  const int ecol = (tid & 3) * 8;          // staging col in elements (16B chunks)
  const unsigned short* gA = A + ((long)r0blk + erow) * (long)K + ecol;
  const unsigned short* gB = Bm + (Brow0 + erow) * (long)K + ecol;
  unsigned short* lA = &smA[tid * 8];      // linear LDS dest (wave-uniform + lane*16)
  unsigned short* lB = &smB[tid * 8];
  const long rowK64 = 64l * (long)K;

  floatx4 acc[4][4] = {};

  const int nk = K >> 5;                   // BK = 32
  for (int kt = 0; kt < nk; ++kt) {
    const int ko = kt * 32;
    lds16(gA + ko, lA);
    lds16(gA + rowK64 + ko, lA + 2048);
    lds16(gB + ko, lB);
    lds16(gB + rowK64 + ko, lB + 2048);
    __syncthreads();                        // compiler drains vmcnt before barrier
    short8 af[4], bfr[4];
#pragma unroll
    for (int m = 0; m < 4; ++m)
      af[m] = *(const short8*)&smA[(wr * 64 + m * 16 + (lane & 15)) * 32 + (lane >> 4) * 8];
#pragma unroll
    for (int n = 0; n < 4; ++n)
      bfr[n] = *(const short8*)&smB[(wc * 64 + n * 16 + (lane & 15)) * 32 + (lane >> 4) * 8];
#pragma unroll
    for (int m = 0; m < 4; ++m)
#pragma unroll
      for (int n = 0; n < 4; ++n)
        acc[m][n] = __builtin_amdgcn_mfma_f32_16x16x32_bf16(af[m], bfr[n], acc[m][n], 0, 0, 0);
    __syncthreads();
  }

  const float sw = (float)fmax(meanw[0], 1e-5);  // ternary weight dequant scale
  const int c0 = blockIdx.x * 128 + wc * 64;
#pragma unroll
  for (int m = 0; m < 4; ++m) {
#pragma unroll
    for (int j = 0; j < 4; ++j) {
      const int lr = wr * 64 + m * 16 + (lane >> 4) * 4 + j;   // block-local row
      const long row = r0blk + lr;
      const float sa = dsA[row] * sw;
      float qs = 0.f, gm = 0.f;
      if (EPI == 1) qs = 127.0f / rmaxin[row];   // rmax pre-clipped
#pragma unroll
      for (int n = 0; n < 4; ++n) {
        const int col = c0 + n * 16 + (lane & 15);
        float v = acc[m][n][j] * sa + bias[col];
        if (EPI == 0) {
          float g = 0.5f * v * (1.0f + erff(v * 0.70710678118654752f));
          gm = fmaxf(gm, fabsf(g));
        } else if (EPI == 1) {
          float g = 0.5f * v * (1.0f + erff(v * 0.70710678118654752f));
          float q = fminf(fmaxf(rintf(g * qs), -128.f), 127.f);
          outh[row * (long)N + col] = f2bf(q);
        } else {
          outf[row * (long)N + col] = v;
        }
      }
      if (EPI == 0) atomicMax(&smx[lr], __builtin_bit_cast(unsigned int, gm));
    }
  }
  if (EPI == 0) {
    __syncthreads();
    if (tid < 128)
      amaxo[(long)(r0blk + tid) * 64 + blockIdx.x] = __builtin_bit_cast(float, smx[tid]);
  }
}

extern "C" void kernel_launch(void* const* d_in, const int* in_sizes, int n_in,
                              void* d_out, int out_size, void* d_ws, size_t ws_size,
                              hipStream_t stream) {
  const float* x     = (const float*)d_in[0];
  const float* gamma = (const float*)d_in[1];
  const float* beta  = (const float*)d_in[2];
  const float* w1    = (const float*)d_in[3];
  const float* b1    = (const float*)d_in[4];
  const float* w2    = (const float*)d_in[5];
  const float* b2    = (const float*)d_in[6];

  char* ws = (char*)d_ws;
  // meta (<256K): part1@0, part2@16K, means@32K, ds1@64K, ds2@128K, rmax@192K
  // [1M)       wq   32M  (wq1, then reused for wq2 after GEMM1 pass B)
  // [1M+32M)   aq   64M
  // [1M+96M)   amax  4M  (16384 rows x 64 col-blocks f32)
  // [1M+100M)  hq  256M  (quantized h, bf16 ints)
  // peak 357 MiB
  double* part1 = (double*)(ws + 0);
  double* part2 = (double*)(ws + 16384);
  double* means = (double*)(ws + 32768);
  float* ds1  = (float*)(ws + 65536);
  float* ds2  = (float*)(ws + 131072);
  float* rmax = (float*)(ws + 196608);
  unsigned short* wq = (unsigned short*)(ws + 1048576l);
  unsigned short* aq = (unsigned short*)(ws + 34603008l);
  float* amax        = (float*)(ws + 101711872l);
  unsigned short* hq = (unsigned short*)(ws + 105906176l);

  const int NW = 16777216;  // elements in each weight matrix

  absmean_partial<<<2048, 256, 0, stream>>>(w1, NW, part1);
  absmean_partial<<<2048, 256, 0, stream>>>(w2, NW, part2);
  absmean_final<<<1, 256, 0, stream>>>(part1, 2048, (double)NW, means + 0);
  absmean_final<<<1, 256, 0, stream>>>(part2, 2048, (double)NW, means + 1);
  wquant_kernel<<<16384, 256, 0, stream>>>(w1, means + 0, wq, NW);
  ln_quant_kernel<<<16384, 256, 0, stream>>>(x, gamma, beta, aq, ds1);

  // GEMM1 pass A: per-row |gelu| partial maxes
  gemm_kernel<0><<<dim3(H_DIM / 128, M_DIM / 128), 256, 0, stream>>>(
      aq, wq, ds1, means + 0, b1, nullptr, nullptr, amax, nullptr, H_DIM, D_DIM);
  rowmax_kernel<<<M_DIM / 4, 256, 0, stream>>>(amax, rmax, ds2);
  // GEMM1 pass B: recompute, quantize at register precision -> bf16 int h
  gemm_kernel<1><<<dim3(H_DIM / 128, M_DIM / 128), 256, 0, stream>>>(
      aq, wq, ds1, means + 0, b1, nullptr, hq, nullptr, rmax, H_DIM, D_DIM);

  // wq slot now free: quantize w2 into it
  wquant_kernel<<<16384, 256, 0, stream>>>(w2, means + 1, wq, NW);

  // GEMM2: out = hq . wq2^T * (ds2*sw2) + b2
  gemm_kernel<2><<<dim3(D_DIM / 128, M_DIM / 128), 256, 0, stream>>>(
      hq, wq, ds2, means + 1, b2, (float*)d_out, nullptr, nullptr, nullptr, D_DIM, H_DIM);
}

// Round 4
// 1989.372 us; speedup vs baseline: 1.2339x; 1.2339x over previous
//
#include <hip/hip_runtime.h>
#include <hip/hip_bf16.h>

// BitNet FFN: LN -> act_quant/ternary-W matmul -> GELU(erf) -> act_quant/ternary-W matmul
// Shapes: x[4,4096,2048] f32, w1[8192,2048], w2[2048,8192], out [16384,2048] f32.
// R4: single-pass GEMM1, M chunked 4x4096. f32 GELU output staged in d_out
// (dead until GEMM2), requantized into dense bf16-int hq. Removes R3's
// duplicate GEMM1 amax pass. GEMMs are bit-exact integer bf16 MFMA
// (ternary weights: |dot| <= 8192*128 < 2^24). Peak ws 353 MiB.

typedef __attribute__((ext_vector_type(8))) short short8;
typedef __attribute__((ext_vector_type(4))) float floatx4;

#define D_DIM 2048
#define H_DIM 8192
#define M_DIM 16384
#define MCHUNK 4096

// ---------- small helpers ----------
__device__ __forceinline__ unsigned short f2bf(float f) {
  unsigned int u = __builtin_bit_cast(unsigned int, f);
  u += 0x7FFFu + ((u >> 16) & 1u);   // RNE; inputs here are never NaN
  return (unsigned short)(u >> 16);
}

__device__ __forceinline__ float block_sum(float v, float* buf) {
#pragma unroll
  for (int o = 32; o > 0; o >>= 1) v += __shfl_down(v, o, 64);
  const int lane = threadIdx.x & 63, w = threadIdx.x >> 6;
  if (lane == 0) buf[w] = v;
  __syncthreads();
  float r = buf[0] + buf[1] + buf[2] + buf[3];
  __syncthreads();
  return r;
}
__device__ __forceinline__ float block_max(float v, float* buf) {
#pragma unroll
  for (int o = 32; o > 0; o >>= 1) v = fmaxf(v, __shfl_down(v, o, 64));
  const int lane = threadIdx.x & 63, w = threadIdx.x >> 6;
  if (lane == 0) buf[w] = v;
  __syncthreads();
  float r = fmaxf(fmaxf(buf[0], buf[1]), fmaxf(buf[2], buf[3]));
  __syncthreads();
  return r;
}

__device__ __forceinline__ void lds16(const unsigned short* g, unsigned short* l) {
  __builtin_amdgcn_global_load_lds(
      (const __attribute__((address_space(1))) unsigned int*)g,
      (__attribute__((address_space(3))) unsigned int*)l, 16, 0, 0);
}

// ---------- weight abs-mean (deterministic two-stage) ----------
__global__ __launch_bounds__(256) void absmean_partial(const float* __restrict__ w,
                                                       int n, double* __restrict__ part) {
  __shared__ float buf[4];
  float s = 0.0f;
  const long stride = (long)gridDim.x * 256 * 4;
  for (long i = ((long)blockIdx.x * 256 + threadIdx.x) * 4; i < n; i += stride) {
    float4 v = *(const float4*)(w + i);
    s += fabsf(v.x) + fabsf(v.y) + fabsf(v.z) + fabsf(v.w);
  }
  float r = block_sum(s, buf);
  if (threadIdx.x == 0) part[blockIdx.x] = (double)r;
}

__global__ __launch_bounds__(256) void absmean_final(const double* __restrict__ part,
                                                     int nb, double n, double* __restrict__ out) {
  __shared__ double buf[4];
  double s = 0.0;
  for (int i = threadIdx.x; i < nb; i += 256) s += part[i];
#pragma unroll
  for (int o = 32; o > 0; o >>= 1) s += __shfl_down(s, o, 64);
  const int lane = threadIdx.x & 63, w = threadIdx.x >> 6;
  if (lane == 0) buf[w] = s;
  __syncthreads();
  if (threadIdx.x == 0) out[0] = (buf[0] + buf[1] + buf[2] + buf[3]) / n;
}

// ---------- ternary weight quant: t = clip(rint(w*s),-1,1), stored as bf16 ----------
__global__ __launch_bounds__(256) void wquant_kernel(const float* __restrict__ w,
                                                     const double* __restrict__ mean,
                                                     unsigned short* __restrict__ wq, int n) {
  long i = ((long)blockIdx.x * 256 + threadIdx.x) * 4;
  if (i >= n) return;
  const float s = 1.0f / (float)fmax(mean[0], 1e-5);
  float4 v = *(const float4*)(w + i);
  ushort4 q;
  q.x = f2bf(fminf(fmaxf(rintf(v.x * s), -1.f), 1.f));
  q.y = f2bf(fminf(fmaxf(rintf(v.y * s), -1.f), 1.f));
  q.z = f2bf(fminf(fmaxf(rintf(v.z * s), -1.f), 1.f));
  q.w = f2bf(fminf(fmaxf(rintf(v.w * s), -1.f), 1.f));
  *(ushort4*)(wq + i) = q;
}

// ---------- fused LayerNorm + per-token int8 absmax quant ----------
__global__ __launch_bounds__(256) void ln_quant_kernel(const float* __restrict__ x,
                                                       const float* __restrict__ gamma,
                                                       const float* __restrict__ beta,
                                                       unsigned short* __restrict__ aq,
                                                       float* __restrict__ ds) {
  __shared__ float buf[4];
  const int t = threadIdx.x;
  const long row = blockIdx.x;
  const float* xr = x + row * (long)D_DIM;
  float v[8];
  *(float4*)(v)     = *(const float4*)(xr + t * 8);
  *(float4*)(v + 4) = *(const float4*)(xr + t * 8 + 4);
  float s = 0.f;
#pragma unroll
  for (int i = 0; i < 8; ++i) s += v[i];
  s = block_sum(s, buf);
  const float mu = s * (1.0f / 2048.0f);
  float sq = 0.f;
#pragma unroll
  for (int i = 0; i < 8; ++i) { float d = v[i] - mu; sq += d * d; }
  sq = block_sum(sq, buf);
  const float inv = 1.0f / sqrtf(sq * (1.0f / 2048.0f) + 1e-5f);
  float gam[8], bet[8];
  *(float4*)(gam)     = *(const float4*)(gamma + t * 8);
  *(float4*)(gam + 4) = *(const float4*)(gamma + t * 8 + 4);
  *(float4*)(bet)     = *(const float4*)(beta + t * 8);
  *(float4*)(bet + 4) = *(const float4*)(beta + t * 8 + 4);
  float xn[8]; float am = 0.f;
#pragma unroll
  for (int i = 0; i < 8; ++i) {
    xn[i] = (v[i] - mu) * inv * gam[i] + bet[i];
    am = fmaxf(am, fabsf(xn[i]));
  }
  am = block_max(am, buf);
  am = fmaxf(am, 1e-5f);
  const float qs = 127.0f / am;
  __align__(16) unsigned short q[8];
#pragma unroll
  for (int i = 0; i < 8; ++i)
    q[i] = f2bf(fminf(fmaxf(rintf(xn[i] * qs), -128.f), 127.f));
  *(ushort4*)(aq + row * D_DIM + t * 8)     = *(ushort4*)(q);
  *(ushort4*)(aq + row * D_DIM + t * 8 + 4) = *(ushort4*)(q + 4);
  if (t == 0) ds[row] = am / 127.0f;
}

// ---------- per-token re-quant from f32 h chunk -> dense bf16 ints ----------
__global__ __launch_bounds__(256) void hquant32_kernel(const float* __restrict__ src,
                                                       unsigned short* __restrict__ dst,
                                                       float* __restrict__ ds2) {
  __shared__ float buf[4];
  const int t = threadIdx.x;
  const long row = blockIdx.x;
  const float* sr = src + row * (long)H_DIM;
  float v[4][8];
#pragma unroll
  for (int c = 0; c < 4; ++c) {
    *(float4*)(v[c])     = *(const float4*)(sr + (c * 256 + t) * 8);
    *(float4*)(v[c] + 4) = *(const float4*)(sr + (c * 256 + t) * 8 + 4);
  }
  float am = 0.f;
#pragma unroll
  for (int c = 0; c < 4; ++c)
#pragma unroll
    for (int i = 0; i < 8; ++i) am = fmaxf(am, fabsf(v[c][i]));
  am = block_max(am, buf);
  am = fmaxf(am, 1e-5f);
  const float qs = 127.0f / am;
  unsigned short* dr = dst + row * (long)H_DIM;
#pragma unroll
  for (int c = 0; c < 4; ++c) {
    short8 o;
#pragma unroll
    for (int i = 0; i < 8; ++i)
      o[i] = (short)f2bf(fminf(fmaxf(rintf(v[c][i] * qs), -128.f), 127.f));
    *(short8*)(dr + (c * 256 + t) * 8) = o;
  }
  if (t == 0) ds2[row] = am / 127.0f;
}

// ---------- m97-style 128x128 GEMM, A[M,K] x B[N,K]^T, templated epilogue ----------
// EPI==1: dequant+bias+exact GELU -> f32 outf   (GEMM1 chunk)
// EPI==2: dequant+bias            -> f32 outf   (GEMM2)
template <int EPI>
__global__ __launch_bounds__(256) void gemm_kernel(const unsigned short* __restrict__ A,
                                                   const unsigned short* __restrict__ Bm,
                                                   const float* __restrict__ dsA,
                                                   const double* __restrict__ meanw,
                                                   const float* __restrict__ bias,
                                                   float* __restrict__ outf,
                                                   int N, int K) {
  __shared__ __align__(16) unsigned short smA[128 * 32];
  __shared__ __align__(16) unsigned short smB[128 * 32];
  const int tid = threadIdx.x;
  const int lane = tid & 63;
  const int wid = tid >> 6;
  const int wr = wid >> 1, wc = wid & 1;   // 2x2 waves, 64x64 each
  const int r0blk = blockIdx.y * 128;
  const long Brow0 = (long)blockIdx.x * 128;

  const int erow = tid >> 2;               // staging row (0..63)
  const int ecol = (tid & 3) * 8;          // staging col in elements (16B chunks)
  const unsigned short* gA = A + ((long)r0blk + erow) * (long)K + ecol;
  const unsigned short* gB = Bm + (Brow0 + erow) * (long)K + ecol;
  unsigned short* lA = &smA[tid * 8];      // linear LDS dest (wave-uniform + lane*16)
  unsigned short* lB = &smB[tid * 8];
  const long rowK64 = 64l * (long)K;

  floatx4 acc[4][4] = {};

  const int nk = K >> 5;                   // BK = 32
  for (int kt = 0; kt < nk; ++kt) {
    const int ko = kt * 32;
    lds16(gA + ko, lA);
    lds16(gA + rowK64 + ko, lA + 2048);
    lds16(gB + ko, lB);
    lds16(gB + rowK64 + ko, lB + 2048);
    __syncthreads();                        // compiler drains vmcnt before barrier
    short8 af[4], bfr[4];
#pragma unroll
    for (int m = 0; m < 4; ++m)
      af[m] = *(const short8*)&smA[(wr * 64 + m * 16 + (lane & 15)) * 32 + (lane >> 4) * 8];
#pragma unroll
    for (int n = 0; n < 4; ++n)
      bfr[n] = *(const short8*)&smB[(wc * 64 + n * 16 + (lane & 15)) * 32 + (lane >> 4) * 8];
#pragma unroll
    for (int m = 0; m < 4; ++m)
#pragma unroll
      for (int n = 0; n < 4; ++n)
        acc[m][n] = __builtin_amdgcn_mfma_f32_16x16x32_bf16(af[m], bfr[n], acc[m][n], 0, 0, 0);
    __syncthreads();
  }

  const float sw = (float)fmax(meanw[0], 1e-5);  // ternary weight dequant scale
  const int c0 = blockIdx.x * 128 + wc * 64;
#pragma unroll
  for (int m = 0; m < 4; ++m) {
#pragma unroll
    for (int j = 0; j < 4; ++j) {
      const long row = r0blk + wr * 64 + m * 16 + (lane >> 4) * 4 + j;
      const float sa = dsA[row] * sw;
#pragma unroll
      for (int n = 0; n < 4; ++n) {
        const int col = c0 + n * 16 + (lane & 15);
        float v = acc[m][n][j] * sa + bias[col];
        if (EPI == 1) {
          float g = 0.5f * v * (1.0f + erff(v * 0.70710678118654752f));
          outf[row * (long)N + col] = g;
        } else {
          outf[row * (long)N + col] = v;
        }
      }
    }
  }
}

extern "C" void kernel_launch(void* const* d_in, const int* in_sizes, int n_in,
                              void* d_out, int out_size, void* d_ws, size_t ws_size,
                              hipStream_t stream) {
  const float* x     = (const float*)d_in[0];
  const float* gamma = (const float*)d_in[1];
  const float* beta  = (const float*)d_in[2];
  const float* w1    = (const float*)d_in[3];
  const float* b1    = (const float*)d_in[4];
  const float* w2    = (const float*)d_in[5];
  const float* b2    = (const float*)d_in[6];

  char* ws = (char*)d_ws;
  // meta (<256K): part1@0, part2@16K, means@32K, ds1@64K, ds2@128K
  // [1M)      wq  32M  (wq1, reused for wq2 after last GEMM1 chunk)
  // [1M+32M)  aq  64M
  // [1M+96M)  hq 256M  (dense quantized h, bf16 ints)
  // peak 353 MiB.  d_out (128M) doubles as f32 GELU staging per M-chunk.
  double* part1 = (double*)(ws + 0);
  double* part2 = (double*)(ws + 16384);
  double* means = (double*)(ws + 32768);
  float* ds1  = (float*)(ws + 65536);
  float* ds2  = (float*)(ws + 131072);
  unsigned short* wq = (unsigned short*)(ws + 1048576l);
  unsigned short* aq = (unsigned short*)(ws + 34603008l);
  unsigned short* hq = (unsigned short*)(ws + 101711872l);

  const int NW = 16777216;  // elements in each weight matrix
  float* hstage = (float*)d_out;  // 4096 x 8192 f32 = 128 MiB, dead until GEMM2

  absmean_partial<<<2048, 256, 0, stream>>>(w1, NW, part1);
  absmean_partial<<<2048, 256, 0, stream>>>(w2, NW, part2);
  absmean_final<<<1, 256, 0, stream>>>(part1, 2048, (double)NW, means + 0);
  absmean_final<<<1, 256, 0, stream>>>(part2, 2048, (double)NW, means + 1);
  wquant_kernel<<<16384, 256, 0, stream>>>(w1, means + 0, wq, NW);
  ln_quant_kernel<<<16384, 256, 0, stream>>>(x, gamma, beta, aq, ds1);

  // GEMM1 in 4 M-chunks: f32 gelu -> d_out staging, requant -> dense hq
  for (int c = 0; c < 4; ++c) {
    const long r0 = (long)c * MCHUNK;
    gemm_kernel<1><<<dim3(H_DIM / 128, MCHUNK / 128), 256, 0, stream>>>(
        aq + r0 * D_DIM, wq, ds1 + r0, means + 0, b1, hstage, H_DIM, D_DIM);
    hquant32_kernel<<<MCHUNK, 256, 0, stream>>>(
        hstage, hq + r0 * H_DIM, ds2 + r0);
  }

  // wq slot now free: quantize w2 into it
  wquant_kernel<<<16384, 256, 0, stream>>>(w2, means + 1, wq, NW);

  // GEMM2: out = hq . wq2^T * (ds2*sw2) + b2
  gemm_kernel<2><<<dim3(D_DIM / 128, M_DIM / 128), 256, 0, stream>>>(
      hq, wq, ds2, means + 1, b2, (float*)d_out, D_DIM, H_DIM);
}

// Round 5
// 1427.963 us; speedup vs baseline: 1.7190x; 1.3932x over previous
//
#include <hip/hip_runtime.h>
#include <hip/hip_bf16.h>

// BitNet FFN: LN -> act_quant/ternary-W matmul -> GELU(erf) -> act_quant/ternary-W matmul
// Shapes: x[4,4096,2048] f32, w1[8192,2048], w2[2048,8192], out [16384,2048] f32.
// R5: GEMMs ported to 256x256 tile, BK=64, 8 waves, double-buffered LDS with
// counted-vmcnt pipeline (T3+T4), LDS XOR-swizzle (T2), setprio (T5), XCD
// block swizzle (T1). Integer-exact bf16 MFMA; accumulation order identical
// to R4 -> output bit-identical (absmax 2.539e-2 expected).
// Peak ws 353 MiB; d_out doubles as f32 GELU staging per M-chunk.

typedef __attribute__((ext_vector_type(8))) short short8;
typedef __attribute__((ext_vector_type(4))) float floatx4;

#define D_DIM 2048
#define H_DIM 8192
#define M_DIM 16384
#define MCHUNK 4096

// ---------- small helpers ----------
__device__ __forceinline__ unsigned short f2bf(float f) {
  unsigned int u = __builtin_bit_cast(unsigned int, f);
  u += 0x7FFFu + ((u >> 16) & 1u);   // RNE; inputs here are never NaN
  return (unsigned short)(u >> 16);
}

__device__ __forceinline__ float block_sum(float v, float* buf) {
#pragma unroll
  for (int o = 32; o > 0; o >>= 1) v += __shfl_down(v, o, 64);
  const int lane = threadIdx.x & 63, w = threadIdx.x >> 6;
  if (lane == 0) buf[w] = v;
  __syncthreads();
  float r = buf[0] + buf[1] + buf[2] + buf[3];
  __syncthreads();
  return r;
}
__device__ __forceinline__ float block_max(float v, float* buf) {
#pragma unroll
  for (int o = 32; o > 0; o >>= 1) v = fmaxf(v, __shfl_down(v, o, 64));
  const int lane = threadIdx.x & 63, w = threadIdx.x >> 6;
  if (lane == 0) buf[w] = v;
  __syncthreads();
  float r = fmaxf(fmaxf(buf[0], buf[1]), fmaxf(buf[2], buf[3]));
  __syncthreads();
  return r;
}

__device__ __forceinline__ void lds16(const unsigned short* g, unsigned short* l) {
  __builtin_amdgcn_global_load_lds(
      (const __attribute__((address_space(1))) unsigned int*)g,
      (__attribute__((address_space(3))) unsigned int*)l, 16, 0, 0);
}

// ---------- weight abs-mean (deterministic two-stage) ----------
__global__ __launch_bounds__(256) void absmean_partial(const float* __restrict__ w,
                                                       int n, double* __restrict__ part) {
  __shared__ float buf[4];
  float s = 0.0f;
  const long stride = (long)gridDim.x * 256 * 4;
  for (long i = ((long)blockIdx.x * 256 + threadIdx.x) * 4; i < n; i += stride) {
    float4 v = *(const float4*)(w + i);
    s += fabsf(v.x) + fabsf(v.y) + fabsf(v.z) + fabsf(v.w);
  }
  float r = block_sum(s, buf);
  if (threadIdx.x == 0) part[blockIdx.x] = (double)r;
}

__global__ __launch_bounds__(256) void absmean_final(const double* __restrict__ part,
                                                     int nb, double n, double* __restrict__ out) {
  __shared__ double buf[4];
  double s = 0.0;
  for (int i = threadIdx.x; i < nb; i += 256) s += part[i];
#pragma unroll
  for (int o = 32; o > 0; o >>= 1) s += __shfl_down(s, o, 64);
  const int lane = threadIdx.x & 63, w = threadIdx.x >> 6;
  if (lane == 0) buf[w] = s;
  __syncthreads();
  if (threadIdx.x == 0) out[0] = (buf[0] + buf[1] + buf[2] + buf[3]) / n;
}

// ---------- ternary weight quant: t = clip(rint(w*s),-1,1), stored as bf16 ----------
__global__ __launch_bounds__(256) void wquant_kernel(const float* __restrict__ w,
                                                     const double* __restrict__ mean,
                                                     unsigned short* __restrict__ wq, int n) {
  long i = ((long)blockIdx.x * 256 + threadIdx.x) * 4;
  if (i >= n) return;
  const float s = 1.0f / (float)fmax(mean[0], 1e-5);
  float4 v = *(const float4*)(w + i);
  ushort4 q;
  q.x = f2bf(fminf(fmaxf(rintf(v.x * s), -1.f), 1.f));
  q.y = f2bf(fminf(fmaxf(rintf(v.y * s), -1.f), 1.f));
  q.z = f2bf(fminf(fmaxf(rintf(v.z * s), -1.f), 1.f));
  q.w = f2bf(fminf(fmaxf(rintf(v.w * s), -1.f), 1.f));
  *(ushort4*)(wq + i) = q;
}

// ---------- fused LayerNorm + per-token int8 absmax quant ----------
__global__ __launch_bounds__(256) void ln_quant_kernel(const float* __restrict__ x,
                                                       const float* __restrict__ gamma,
                                                       const float* __restrict__ beta,
                                                       unsigned short* __restrict__ aq,
                                                       float* __restrict__ ds) {
  __shared__ float buf[4];
  const int t = threadIdx.x;
  const long row = blockIdx.x;
  const float* xr = x + row * (long)D_DIM;
  float v[8];
  *(float4*)(v)     = *(const float4*)(xr + t * 8);
  *(float4*)(v + 4) = *(const float4*)(xr + t * 8 + 4);
  float s = 0.f;
#pragma unroll
  for (int i = 0; i < 8; ++i) s += v[i];
  s = block_sum(s, buf);
  const float mu = s * (1.0f / 2048.0f);
  float sq = 0.f;
#pragma unroll
  for (int i = 0; i < 8; ++i) { float d = v[i] - mu; sq += d * d; }
  sq = block_sum(sq, buf);
  const float inv = 1.0f / sqrtf(sq * (1.0f / 2048.0f) + 1e-5f);
  float gam[8], bet[8];
  *(float4*)(gam)     = *(const float4*)(gamma + t * 8);
  *(float4*)(gam + 4) = *(const float4*)(gamma + t * 8 + 4);
  *(float4*)(bet)     = *(const float4*)(beta + t * 8);
  *(float4*)(bet + 4) = *(const float4*)(beta + t * 8 + 4);
  float xn[8]; float am = 0.f;
#pragma unroll
  for (int i = 0; i < 8; ++i) {
    xn[i] = (v[i] - mu) * inv * gam[i] + bet[i];
    am = fmaxf(am, fabsf(xn[i]));
  }
  am = block_max(am, buf);
  am = fmaxf(am, 1e-5f);
  const float qs = 127.0f / am;
  __align__(16) unsigned short q[8];
#pragma unroll
  for (int i = 0; i < 8; ++i)
    q[i] = f2bf(fminf(fmaxf(rintf(xn[i] * qs), -128.f), 127.f));
  *(ushort4*)(aq + row * D_DIM + t * 8)     = *(ushort4*)(q);
  *(ushort4*)(aq + row * D_DIM + t * 8 + 4) = *(ushort4*)(q + 4);
  if (t == 0) ds[row] = am / 127.0f;
}

// ---------- per-token re-quant from f32 h chunk -> dense bf16 ints ----------
__global__ __launch_bounds__(256) void hquant32_kernel(const float* __restrict__ src,
                                                       unsigned short* __restrict__ dst,
                                                       float* __restrict__ ds2) {
  __shared__ float buf[4];
  const int t = threadIdx.x;
  const long row = blockIdx.x;
  const float* sr = src + row * (long)H_DIM;
  float v[4][8];
#pragma unroll
  for (int c = 0; c < 4; ++c) {
    *(float4*)(v[c])     = *(const float4*)(sr + (c * 256 + t) * 8);
    *(float4*)(v[c] + 4) = *(const float4*)(sr + (c * 256 + t) * 8 + 4);
  }
  float am = 0.f;
#pragma unroll
  for (int c = 0; c < 4; ++c)
#pragma unroll
    for (int i = 0; i < 8; ++i) am = fmaxf(am, fabsf(v[c][i]));
  am = block_max(am, buf);
  am = fmaxf(am, 1e-5f);
  const float qs = 127.0f / am;
  unsigned short* dr = dst + row * (long)H_DIM;
#pragma unroll
  for (int c = 0; c < 4; ++c) {
    short8 o;
#pragma unroll
    for (int i = 0; i < 8; ++i)
      o[i] = (short)f2bf(fminf(fmaxf(rintf(v[c][i] * qs), -128.f), 127.f));
    *(short8*)(dr + (c * 256 + t) * 8) = o;
  }
  if (t == 0) ds2[row] = am / 127.0f;
}

// ---------- 256x256 BK=64 counted-vmcnt pipelined GEMM, A[M,K] x B[N,K]^T ----------
// 8 waves (2M x 4N), each owns 128x64 output. Double-buffered 128KiB LDS.
// T2 granule swizzle: LDS granule g holds global granule g^(row&7) (both sides).
// EPI==1: dequant+bias+exact GELU -> f32 outf   (GEMM1 chunk)
// EPI==2: dequant+bias            -> f32 outf   (GEMM2)
template <int EPI>
__global__ __launch_bounds__(512, 2) void gemm256_kernel(
    const unsigned short* __restrict__ A,
    const unsigned short* __restrict__ Bm,
    const float* __restrict__ dsA,
    const double* __restrict__ meanw,
    const float* __restrict__ bias,
    float* __restrict__ outf,
    int NBX, int N, int K) {
  __shared__ __align__(16) unsigned short smA[2][256 * 64];
  __shared__ __align__(16) unsigned short smB[2][256 * 64];
  const int tid = threadIdx.x;
  const int lane = tid & 63;
  const int wid = tid >> 6;
  const int wr = wid >> 2;    // 0..1 (M quadrant of 128 rows)
  const int wcn = wid & 3;    // 0..3 (N quadrant of 64 cols)

  // T1: XCD-aware bijective block swizzle (gridDim.x % 8 == 0 here: 512)
  const int cpx = gridDim.x >> 3;
  const int swz = ((int)blockIdx.x & 7) * cpx + ((int)blockIdx.x >> 3);
  const int bx = swz % NBX, by = swz / NBX;

  const long r0 = (long)by * 256;
  const long c0 = (long)bx * 256;

  // staging geometry: thread covers granule (sr, tid&7) x 4 row-blocks; source
  // granule pre-swizzled so linear global_load_lds dest realizes the XOR layout.
  const int sr = tid >> 3;                        // row 0..63 within 64-row block
  const int gn = (tid & 7) ^ (sr & 7);            // pre-swizzled source granule
  const unsigned short* gA = A + (r0 + sr) * (long)K + gn * 8;
  const unsigned short* gB = Bm + (c0 + sr) * (long)K + gn * 8;
  const long rowK64 = 64l * (long)K;

  // fragment-read geometry
  const int frow = lane & 15;
  const int fg0 = (lane >> 4) ^ (lane & 7);       // swizzled granule for ks=0

  floatx4 acc[8][4] = {};
  const int nk = K >> 6;                          // BK = 64

#define STAGE256(kt_, c_) {                                           \
    const long ko_ = (long)(kt_) * 64;                                \
    unsigned short* dA_ = &smA[c_][tid * 8];                          \
    unsigned short* dB_ = &smB[c_][tid * 8];                          \
    lds16(gA + ko_,              dA_);                                \
    lds16(gA + ko_ + rowK64,     dA_ + 4096);                         \
    lds16(gA + ko_ + 2 * rowK64, dA_ + 8192);                         \
    lds16(gA + ko_ + 3 * rowK64, dA_ + 12288);                        \
    lds16(gB + ko_,              dB_);                                \
    lds16(gB + ko_ + rowK64,     dB_ + 4096);                         \
    lds16(gB + ko_ + 2 * rowK64, dB_ + 8192);                         \
    lds16(gB + ko_ + 3 * rowK64, dB_ + 12288);                        \
  }

  // prologue: stage K-tiles 0 and 1; wait tile 0 (8 of 16 retire), publish.
  STAGE256(0, 0);
  STAGE256(1, 1);
  asm volatile("s_waitcnt vmcnt(8)" ::: "memory");
  __builtin_amdgcn_s_barrier();
  __builtin_amdgcn_sched_barrier(0);

  for (int kt = 0; kt < nk; ++kt) {
    const int c = kt & 1;
    const unsigned short* pA = smA[c];
    const unsigned short* pB = smB[c];
    short8 af[8], bf[4];

    // ---- phase A: ks = 0 (k-cols 0..31 of this K-tile) ----
    {
      const int g = fg0;
#pragma unroll
      for (int m = 0; m < 8; ++m)
        af[m] = *(const short8*)&pA[(wr * 128 + m * 16 + frow) * 64 + g * 8];
#pragma unroll
      for (int n = 0; n < 4; ++n)
        bf[n] = *(const short8*)&pB[(wcn * 64 + n * 16 + frow) * 64 + g * 8];
      asm volatile("s_waitcnt lgkmcnt(0)" ::: "memory");
      __builtin_amdgcn_sched_barrier(0);
      __builtin_amdgcn_s_setprio(1);
#pragma unroll
      for (int m = 0; m < 8; ++m)
#pragma unroll
        for (int n = 0; n < 4; ++n)
          acc[m][n] = __builtin_amdgcn_mfma_f32_16x16x32_bf16(af[m], bf[n], acc[m][n], 0, 0, 0);
      __builtin_amdgcn_s_setprio(0);
    }

    // ---- phase B: ks = 1 (k-cols 32..63), stage kt+2, counted vmcnt ----
    {
      const int g = fg0 ^ 4;
#pragma unroll
      for (int m = 0; m < 8; ++m)
        af[m] = *(const short8*)&pA[(wr * 128 + m * 16 + frow) * 64 + g * 8];
#pragma unroll
      for (int n = 0; n < 4; ++n)
        bf[n] = *(const short8*)&pB[(wcn * 64 + n * 16 + frow) * 64 + g * 8];
      asm volatile("s_waitcnt lgkmcnt(0)" ::: "memory");
      __builtin_amdgcn_sched_barrier(0);
      // all waves finished reading buf c -> safe to overwrite it
      __builtin_amdgcn_s_barrier();
      __builtin_amdgcn_sched_barrier(0);
      if (kt + 2 < nk) STAGE256(kt + 2, c);
      __builtin_amdgcn_s_setprio(1);
#pragma unroll
      for (int m = 0; m < 8; ++m)
#pragma unroll
        for (int n = 0; n < 4; ++n)
          acc[m][n] = __builtin_amdgcn_mfma_f32_16x16x32_bf16(af[m], bf[n], acc[m][n], 0, 0, 0);
      __builtin_amdgcn_s_setprio(0);
      // wait next tile's loads (leave kt+2's 8 in flight), publish to all waves
      if (kt + 2 < nk) {
        asm volatile("s_waitcnt vmcnt(8)" ::: "memory");
      } else if (kt + 1 < nk) {
        asm volatile("s_waitcnt vmcnt(0)" ::: "memory");
      }
      if (kt + 1 < nk) {
        __builtin_amdgcn_s_barrier();
        __builtin_amdgcn_sched_barrier(0);
      }
    }
  }
#undef STAGE256

  // ---- epilogue ----
  const float sw = (float)fmax(meanw[0], 1e-5);
#pragma unroll
  for (int m = 0; m < 8; ++m) {
#pragma unroll
    for (int j = 0; j < 4; ++j) {
      const long row = r0 + wr * 128 + m * 16 + (lane >> 4) * 4 + j;
      const float sa = dsA[row] * sw;
#pragma unroll
      for (int n = 0; n < 4; ++n) {
        const long col = c0 + wcn * 64 + n * 16 + (lane & 15);
        float v = acc[m][n][j] * sa + bias[col];
        if (EPI == 1) {
          float gl = 0.5f * v * (1.0f + erff(v * 0.70710678118654752f));
          outf[row * (long)N + col] = gl;
        } else {
          outf[row * (long)N + col] = v;
        }
      }
    }
  }
}

extern "C" void kernel_launch(void* const* d_in, const int* in_sizes, int n_in,
                              void* d_out, int out_size, void* d_ws, size_t ws_size,
                              hipStream_t stream) {
  const float* x     = (const float*)d_in[0];
  const float* gamma = (const float*)d_in[1];
  const float* beta  = (const float*)d_in[2];
  const float* w1    = (const float*)d_in[3];
  const float* b1    = (const float*)d_in[4];
  const float* w2    = (const float*)d_in[5];
  const float* b2    = (const float*)d_in[6];

  char* ws = (char*)d_ws;
  // meta (<256K): part1@0, part2@16K, means@32K, ds1@64K, ds2@128K
  // [1M)      wq  32M  (wq1, reused for wq2 after last GEMM1 chunk)
  // [1M+32M)  aq  64M
  // [1M+96M)  hq 256M  (dense quantized h, bf16 ints)
  // peak 353 MiB.  d_out (128M) doubles as f32 GELU staging per M-chunk.
  double* part1 = (double*)(ws + 0);
  double* part2 = (double*)(ws + 16384);
  double* means = (double*)(ws + 32768);
  float* ds1  = (float*)(ws + 65536);
  float* ds2  = (float*)(ws + 131072);
  unsigned short* wq = (unsigned short*)(ws + 1048576l);
  unsigned short* aq = (unsigned short*)(ws + 34603008l);
  unsigned short* hq = (unsigned short*)(ws + 101711872l);

  const int NW = 16777216;  // elements in each weight matrix
  float* hstage = (float*)d_out;  // 4096 x 8192 f32 = 128 MiB, dead until GEMM2

  absmean_partial<<<2048, 256, 0, stream>>>(w1, NW, part1);
  absmean_partial<<<2048, 256, 0, stream>>>(w2, NW, part2);
  absmean_final<<<1, 256, 0, stream>>>(part1, 2048, (double)NW, means + 0);
  absmean_final<<<1, 256, 0, stream>>>(part2, 2048, (double)NW, means + 1);
  wquant_kernel<<<16384, 256, 0, stream>>>(w1, means + 0, wq, NW);
  ln_quant_kernel<<<16384, 256, 0, stream>>>(x, gamma, beta, aq, ds1);

  // GEMM1 in 4 M-chunks: f32 gelu -> d_out staging, requant -> dense hq
  for (int c = 0; c < 4; ++c) {
    const long r0 = (long)c * MCHUNK;
    gemm256_kernel<1><<<(H_DIM / 256) * (MCHUNK / 256), 512, 0, stream>>>(
        aq + r0 * D_DIM, wq, ds1 + r0, means + 0, b1, hstage,
        H_DIM / 256, H_DIM, D_DIM);
    hquant32_kernel<<<MCHUNK, 256, 0, stream>>>(
        hstage, hq + r0 * H_DIM, ds2 + r0);
  }

  // wq slot now free: quantize w2 into it
  wquant_kernel<<<16384, 256, 0, stream>>>(w2, means + 1, wq, NW);

  // GEMM2: out = hq . wq2^T * (ds2*sw2) + b2
  gemm256_kernel<2><<<(D_DIM / 256) * (M_DIM / 256), 512, 0, stream>>>(
      hq, wq, ds2, means + 1, b2, (float*)d_out,
      D_DIM / 256, D_DIM, H_DIM);
}